// Round 2
// baseline (2428.988 us; speedup 1.0000x reference)
//
#include <hip/hip_runtime.h>

#define BB 16
#define CC 128
#define HH 112
#define NHH 4
#define HDD 32
#define WSZ 7
#define NN 49
#define SH 3

__device__ __forceinline__ int rid3(int p) { return p < 105 ? 0 : (p < 109 ? 1 : 2); }

// ---------------- patch embed: 4x4 stride-4 conv ----------------
// grid = B*H (1792), block = 256
__global__ __launch_bounds__(256) void conv_embed(const float* __restrict__ x,
    const float* __restrict__ cw, const float* __restrict__ cb, float* __restrict__ t) {
  __shared__ float xs[3][4][448];   // one output row's input patch rows
  __shared__ float wT[48][128];     // weights transposed [k][c]
  __shared__ float cbs[128];
  int bid = blockIdx.x;
  int b = bid / HH, oh = bid % HH;
  int tid = threadIdx.x;
  for (int idx = tid; idx < 3 * 4 * 448; idx += 256) {
    int ch = idx / 1792;
    int r = (idx / 448) & 3;
    int col = idx % 448;
    xs[ch][r][col] = x[((b * 3 + ch) * 448 + (oh * 4 + r)) * 448 + col];
  }
  for (int idx = tid; idx < 6144; idx += 256) {
    int c = idx / 48, k = idx - c * 48;
    wT[k][c] = cw[idx];
  }
  if (tid < 128) cbs[tid] = cb[tid];
  __syncthreads();
  int c0 = (tid & 31) << 2;  // 4 filters
  int gg = tid >> 5;         // 8 gw groups
  for (int it = 0; it < 4; ++it) {
    int gw0 = it * 32 + gg * 4;
    if (gw0 >= HH) break;
    float acc[4][4] = {};
#pragma unroll
    for (int k = 0; k < 48; ++k) {
      int ch = k >> 4, r = (k >> 2) & 3, j = k & 3;
      float4 wv = *(const float4*)&wT[k][c0];
#pragma unroll
      for (int d = 0; d < 4; ++d) {
        float xv = xs[ch][r][(gw0 + d) * 4 + j];
        acc[d][0] = fmaf(xv, wv.x, acc[d][0]);
        acc[d][1] = fmaf(xv, wv.y, acc[d][1]);
        acc[d][2] = fmaf(xv, wv.z, acc[d][2]);
        acc[d][3] = fmaf(xv, wv.w, acc[d][3]);
      }
    }
    float4 bv = *(const float4*)&cbs[c0];
#pragma unroll
    for (int d = 0; d < 4; ++d) {
      int gw = gw0 + d;
      if (gw < HH) {
        float4 o4;
        o4.x = acc[d][0] + bv.x; o4.y = acc[d][1] + bv.y;
        o4.z = acc[d][2] + bv.z; o4.w = acc[d][3] + bv.w;
        *(float4*)&t[((b * HH + oh) * HH + gw) * CC + c0] = o4;
      }
    }
  }
}

// ---------------- relative position bias tables ----------------
// grid = 2 (layers), block = 256; bg[l][h][i][j]
__global__ void bias_table(const float* __restrict__ rpb, float* __restrict__ bg) {
  int l = blockIdx.x;
  for (int idx = threadIdx.x; idx < NHH * NN * NN; idx += blockDim.x) {
    int h = idx / (NN * NN);
    int r2 = idx - h * NN * NN;
    int i = r2 / NN, j = r2 - (r2 / NN) * NN;
    int rel = ((i / 7) - (j / 7) + 6) * 13 + ((i % 7) - (j % 7) + 6);
    bg[l * NHH * NN * NN + idx] = rpb[(l * 169 + rel) * NHH + h];
  }
}

// ---------------- fused window layer ----------------
// grid = B*nW = 4096 blocks, block = 256 (4 waves = 4 heads in attn phase)
// LDS: win[52][132] | Wb[64][132] | qkvL[3][52][132].
// bias (9604 floats) overlays win+Wb (15312 floats) AFTER the QKV GEMM — no
// overlap with qkvL (round-0 bug: scores spilled into qkvL; scores are now
// per-lane registers with fully-unrolled loops).
__global__ __launch_bounds__(256, 1) void swin_layer(
    const float* tin, float* toutB, float* __restrict__ outN,
    const float* __restrict__ qw, const float* __restrict__ qb,
    const float* __restrict__ pw, const float* __restrict__ pb,
    const float* __restrict__ bg, int shift, int writeN) {
  __shared__ float sm[35904];  // 143,616 B
  float (*win)[132] = (float(*)[132])sm;                              // 52x132
  float (*Wb)[132] = (float(*)[132])(sm + 52 * 132);                  // 64x132
  float (*qkvL)[52][132] = (float(*)[52][132])(sm + (52 + 64) * 132); // 3x52x132
  float* biasS = sm;  // 9604 floats, overlays win+Wb (dead after QKV GEMM)

  int tid = threadIdx.x;
  int wid = blockIdx.x;
  int b = wid >> 8;
  int wh = (wid >> 4) & 15, ww = wid & 15;

  // stage window tokens (rolled gather for shifted layer); rows 49..51 zero
  for (int idx = tid; idx < 52 * 128; idx += 256) {
    int n = idx >> 7, k = idx & 127;
    float v = 0.f;
    if (n < NN) {
      int gh = wh * WSZ + n / 7 + shift; if (gh >= HH) gh -= HH;
      int gw = ww * WSZ + n % 7 + shift; if (gw >= HH) gw -= HH;
      v = tin[((b * HH + gh) * HH + gw) * CC + k];
    }
    win[n][k] = v;
  }
  // zero dummy rows of qkvL[0] (proj reads rows 48..51)
  for (int idx = tid; idx < 3 * 132; idx += 256)
    qkvL[0][49 + idx / 132][idx % 132] = 0.f;
  __syncthreads();

  int nt = tid >> 4, ot = tid & 15;  // 13 n-tiles (x4 rows), 16 col-threads

  // ---- QKV GEMM: 6 chunks of 64 output cols, K=128 ----
  // thread (nt,ot) computes rows n0..n0+3, cols {ot,ot+16,ot+32,ot+48} of chunk
  for (int ccn = 0; ccn < 6; ++ccn) {
    for (int idx = tid; idx < 64 * 128; idx += 256)
      Wb[idx >> 7][idx & 127] = qw[ccn * 64 * 128 + idx];
    __syncthreads();
    if (nt < 13) {
      int n0 = nt * 4;
      float acc[4][4] = {};  // [d][e]
#pragma unroll 4
      for (int k = 0; k < 128; k += 4) {
        float4 av[4], wv[4];
#pragma unroll
        for (int d = 0; d < 4; ++d) av[d] = *(const float4*)&win[n0 + d][k];
#pragma unroll
        for (int e = 0; e < 4; ++e) wv[e] = *(const float4*)&Wb[ot + 16 * e][k];
#pragma unroll
        for (int d = 0; d < 4; ++d)
#pragma unroll
          for (int e = 0; e < 4; ++e) {
            acc[d][e] = fmaf(av[d].x, wv[e].x, acc[d][e]);
            acc[d][e] = fmaf(av[d].y, wv[e].y, acc[d][e]);
            acc[d][e] = fmaf(av[d].z, wv[e].z, acc[d][e]);
            acc[d][e] = fmaf(av[d].w, wv[e].w, acc[d][e]);
          }
      }
      int oBase = ccn * 64;
      int sec = oBase >> 7, colB = oBase & 127;
#pragma unroll
      for (int e = 0; e < 4; ++e) {
        float bb = qb[oBase + ot + 16 * e];
#pragma unroll
        for (int d = 0; d < 4; ++d) {
          int n = n0 + d;
          if (n < NN) qkvL[sec][n][colB + ot + 16 * e] = acc[d][e] + bb;
        }
      }
    }
    __syncthreads();
  }

  // ---- stage bias table (overlays win/Wb — both dead) ----
  for (int idx = tid; idx < NHH * NN * NN; idx += 256) biasS[idx] = bg[idx];
  __syncthreads();

  // ---- attention: wave = head, lane = query row; scores in registers ----
  {
    int h = tid >> 6, i = tid & 63;
    if (i < NN) {
      float qr[32];
#pragma unroll
      for (int e = 0; e < 8; ++e) {
        float4 q4 = *(const float4*)&qkvL[0][i][h * HDD + e * 4];
        qr[e * 4 + 0] = q4.x; qr[e * 4 + 1] = q4.y;
        qr[e * 4 + 2] = q4.z; qr[e * 4 + 3] = q4.w;
      }
      int regi = 0;
      if (shift) regi = rid3(wh * WSZ + i / 7) * 3 + rid3(ww * WSZ + i % 7);
      const float* brow = &biasS[(h * NN + i) * NN];
      float srow[NN];
      float mx = -1e30f;
#pragma unroll
      for (int j = 0; j < NN; ++j) {
        float s0 = 0.f, s1 = 0.f, s2 = 0.f, s3 = 0.f;
#pragma unroll
        for (int e = 0; e < 8; ++e) {
          float4 k4 = *(const float4*)&qkvL[1][j][h * HDD + e * 4];  // uniform addr: broadcast
          s0 = fmaf(qr[e * 4 + 0], k4.x, s0);
          s1 = fmaf(qr[e * 4 + 1], k4.y, s1);
          s2 = fmaf(qr[e * 4 + 2], k4.z, s2);
          s3 = fmaf(qr[e * 4 + 3], k4.w, s3);
        }
        float s = (s0 + s1) + (s2 + s3);
        s = s * 0.17677669529663687f + brow[j];
        if (shift) {
          int regj = rid3(wh * WSZ + j / 7) * 3 + rid3(ww * WSZ + j % 7);
          if (regj != regi) s -= 100.f;
        }
        srow[j] = s;
        mx = fmaxf(mx, s);
      }
      float sum = 0.f;
#pragma unroll
      for (int j = 0; j < NN; ++j) {
        float e = __expf(srow[j] - mx);
        srow[j] = e;
        sum += e;
      }
      float inv = 1.f / sum;
      float out[32] = {};
#pragma unroll
      for (int j = 0; j < NN; ++j) {
        float pj = srow[j];
#pragma unroll
        for (int e = 0; e < 8; ++e) {
          float4 v4 = *(const float4*)&qkvL[2][j][h * HDD + e * 4];  // uniform addr: broadcast
          out[e * 4 + 0] = fmaf(pj, v4.x, out[e * 4 + 0]);
          out[e * 4 + 1] = fmaf(pj, v4.y, out[e * 4 + 1]);
          out[e * 4 + 2] = fmaf(pj, v4.z, out[e * 4 + 2]);
          out[e * 4 + 3] = fmaf(pj, v4.w, out[e * 4 + 3]);
        }
      }
      // aout overwrites own head's q columns (only this lane touched row i)
#pragma unroll
      for (int e = 0; e < 8; ++e) {
        float4 o4;
        o4.x = out[e * 4 + 0] * inv; o4.y = out[e * 4 + 1] * inv;
        o4.z = out[e * 4 + 2] * inv; o4.w = out[e * 4 + 3] * inv;
        *(float4*)&qkvL[0][i][h * HDD + e * 4] = o4;
      }
    }
  }
  __syncthreads();

  // ---- proj GEMM: 2 chunks of 64 cols, K=128; fused store ----
  for (int pc = 0; pc < 2; ++pc) {
    for (int idx = tid; idx < 64 * 128; idx += 256)
      Wb[idx >> 7][idx & 127] = pw[pc * 64 * 128 + idx];
    __syncthreads();
    if (nt < 13) {
      int n0 = nt * 4;
      float acc[4][4] = {};
#pragma unroll 4
      for (int k = 0; k < 128; k += 4) {
        float4 av[4], wv[4];
#pragma unroll
        for (int d = 0; d < 4; ++d) av[d] = *(const float4*)&qkvL[0][n0 + d][k];
#pragma unroll
        for (int e = 0; e < 4; ++e) wv[e] = *(const float4*)&Wb[ot + 16 * e][k];
#pragma unroll
        for (int d = 0; d < 4; ++d)
#pragma unroll
          for (int e = 0; e < 4; ++e) {
            acc[d][e] = fmaf(av[d].x, wv[e].x, acc[d][e]);
            acc[d][e] = fmaf(av[d].y, wv[e].y, acc[d][e]);
            acc[d][e] = fmaf(av[d].z, wv[e].z, acc[d][e]);
            acc[d][e] = fmaf(av[d].w, wv[e].w, acc[d][e]);
          }
      }
#pragma unroll
      for (int d = 0; d < 4; ++d) {
        int n = n0 + d;
        if (n < NN) {
          int gh = wh * WSZ + n / 7 + shift; if (gh >= HH) gh -= HH;
          int gw = ww * WSZ + n % 7 + shift; if (gw >= HH) gw -= HH;
#pragma unroll
          for (int e = 0; e < 4; ++e) {
            int o = pc * 64 + ot + 16 * e;
            float val = acc[d][e] + pb[o];
            if (!writeN) {
              toutB[((b * HH + gh) * HH + gw) * CC + o] = val;
            } else {
              outN[((b * CC + o) * HH + gh) * HH + gw] = val;
            }
          }
        }
      }
    }
    __syncthreads();
  }
}

extern "C" void kernel_launch(void* const* d_in, const int* in_sizes, int n_in,
                              void* d_out, int out_size, void* d_ws, size_t ws_size,
                              hipStream_t stream) {
  const float* x = (const float*)d_in[0];
  const float* cw = (const float*)d_in[1];
  const float* cb = (const float*)d_in[2];
  const float* qkvw = (const float*)d_in[3];  // (2,384,128)
  const float* qkvb = (const float*)d_in[4];  // (2,384)
  const float* projw = (const float*)d_in[5]; // (2,128,128)
  const float* projb = (const float*)d_in[6]; // (2,128)
  const float* rpb = (const float*)d_in[7];   // (2,169,4)
  float* out = (float*)d_out;

  float* t = (float*)d_ws;                         // (16,112,112,128) fp32
  float* biasG = t + (size_t)BB * HH * HH * CC;    // 2*4*49*49 floats

  conv_embed<<<BB * HH, 256, 0, stream>>>(x, cw, cb, t);
  bias_table<<<2, 256, 0, stream>>>(rpb, biasG);

  // layer 0: no shift, in-place on t (windows partition tokens -> safe)
  swin_layer<<<4096, 256, 0, stream>>>(t, t, nullptr,
      qkvw, qkvb, projw, projb, biasG, 0, 0);
  // layer 1: shift=3, fused NCHW transpose into d_out
  swin_layer<<<4096, 256, 0, stream>>>(t, nullptr, out,
      qkvw + 384 * 128, qkvb + 384, projw + 128 * 128, projb + 128,
      biasG + NHH * NN * NN, SH, 1);
}

// Round 3
// 317.134 us; speedup vs baseline: 7.6592x; 7.6592x over previous
//
#include <hip/hip_runtime.h>

#define BB 16
#define CC 128
#define HH 112
#define NHH 4
#define WSZ 7
#define NN 49
#define SH 3

typedef _Float16 h8 __attribute__((ext_vector_type(8)));
typedef _Float16 h4 __attribute__((ext_vector_type(4)));
typedef float f4 __attribute__((ext_vector_type(4)));

__device__ __forceinline__ int rid3(int p) { return p < 105 ? 0 : (p < 109 ? 1 : 2); }

// LDS regions (element offsets, _Float16):
//  win [64][136]      @ 0      (8704)
//  K   [4][64][40]    @ 8704   (10240)
//  Q   [4][64][40]    @ 18944  (10240)
//  VT  [4][32][72]    @ 29184  (9216)   total 38400 elems = 76800 B
// overlays: P [4][64][72] @ 0 (18432 <= win+K); O [64][136] @ 18944 (8704 <= Q)
#define OFF_WIN 0
#define OFF_K   8704
#define OFF_Q   18944
#define OFF_VT  29184
#define OFF_P   0
#define OFF_O   18944

// ---------------- patch embed: 4x4 stride-4 conv -> t0 (fp16, [B,H,W,C]) ----
__global__ __launch_bounds__(256) void conv_embed(const float* __restrict__ x,
    const float* __restrict__ cw, const float* __restrict__ cb, _Float16* __restrict__ t0) {
  __shared__ float xs[3][4][448];
  __shared__ float wT[48][128];
  __shared__ float cbs[128];
  int bid = blockIdx.x;
  int b = bid / HH, oh = bid % HH;
  int tid = threadIdx.x;
  for (int idx = tid; idx < 3 * 4 * 448; idx += 256) {
    int ch = idx / 1792;
    int r = (idx / 448) & 3;
    int col = idx % 448;
    xs[ch][r][col] = x[((b * 3 + ch) * 448 + (oh * 4 + r)) * 448 + col];
  }
  for (int idx = tid; idx < 6144; idx += 256) {
    int c = idx / 48, k = idx - c * 48;
    wT[k][c] = cw[idx];
  }
  if (tid < 128) cbs[tid] = cb[tid];
  __syncthreads();
  int c0 = (tid & 31) << 2;
  int gg = tid >> 5;
  for (int it = 0; it < 4; ++it) {
    int gw0 = it * 32 + gg * 4;
    if (gw0 >= HH) break;
    float acc[4][4] = {};
#pragma unroll
    for (int k = 0; k < 48; ++k) {
      int ch = k >> 4, r = (k >> 2) & 3, j = k & 3;
      float4 wv = *(const float4*)&wT[k][c0];
#pragma unroll
      for (int d = 0; d < 4; ++d) {
        float xv = xs[ch][r][(gw0 + d) * 4 + j];
        acc[d][0] = fmaf(xv, wv.x, acc[d][0]);
        acc[d][1] = fmaf(xv, wv.y, acc[d][1]);
        acc[d][2] = fmaf(xv, wv.z, acc[d][2]);
        acc[d][3] = fmaf(xv, wv.w, acc[d][3]);
      }
    }
    float4 bv = *(const float4*)&cbs[c0];
#pragma unroll
    for (int d = 0; d < 4; ++d) {
      int gw = gw0 + d;
      h4 o;
      o[0] = (_Float16)(acc[d][0] + bv.x); o[1] = (_Float16)(acc[d][1] + bv.y);
      o[2] = (_Float16)(acc[d][2] + bv.z); o[3] = (_Float16)(acc[d][3] + bv.w);
      *(h4*)&t0[((size_t)(b * HH + oh) * HH + gw) * CC + c0] = o;
    }
  }
}

// ---------------- prep: fp16 weights (Q-scale folded), scaled qb, bias table ----
// biasT layout: [layer][h][jt][it][lane][r] f32  (matches S^T C-fragment)
__global__ void prep(const float* __restrict__ qw, const float* __restrict__ qb,
                     const float* __restrict__ pw, const float* __restrict__ rpb,
                     _Float16* __restrict__ qwh, float* __restrict__ qbs,
                     _Float16* __restrict__ pwh, float* __restrict__ biasT) {
  const float scale = 0.17677669529663687f;  // 1/sqrt(32)
  int tid0 = blockIdx.x * blockDim.x + threadIdx.x;
  int stride = gridDim.x * blockDim.x;
  for (int idx = tid0; idx < 2 * 384 * 128; idx += stride) {
    int n = (idx >> 7) % 384;
    float v = qw[idx];
    if (n < 128) v *= scale;
    qwh[idx] = (_Float16)v;
  }
  for (int idx = tid0; idx < 2 * 384; idx += stride) {
    int n = idx % 384;
    float v = qb[idx];
    if (n < 128) v *= scale;
    qbs[idx] = v;
  }
  for (int idx = tid0; idx < 2 * 128 * 128; idx += stride)
    pwh[idx] = (_Float16)pw[idx];
  for (int idx = tid0; idx < 2 * 4 * 4 * 4 * 64 * 4; idx += stride) {
    int r = idx & 3;
    int lane = (idx >> 2) & 63;
    int it = (idx >> 8) & 3;
    int jt = (idx >> 10) & 3;
    int hh = (idx >> 12) & 3;
    int ll = idx >> 14;
    int i = it * 16 + (lane & 15);
    int j = jt * 16 + ((lane >> 4) * 4) + r;
    float v = 0.f;
    if (i < NN && j < NN) {
      int rel = ((i / 7 - j / 7) + 6) * 13 + ((i % 7 - j % 7) + 6);
      v = rpb[(ll * 169 + rel) * NHH + hh];
    }
    biasT[idx] = v;
  }
}

// ---------------- fused window layer (MFMA fp16) ----------------
// grid = 4096 (1 block = 1 window), 256 thr = 4 waves; wave = head in attn.
__global__ __launch_bounds__(256, 2) void swin_layer(
    const _Float16* __restrict__ tin, _Float16* __restrict__ toutB, float* __restrict__ outN,
    const _Float16* __restrict__ qwh, const float* __restrict__ qbs,
    const _Float16* __restrict__ pwh, const float* __restrict__ pb,
    const float* __restrict__ biasT, int shift, int writeN) {
  __shared__ _Float16 sm[38400];  // 76800 B

  int tid = threadIdx.x;
  int wid = blockIdx.x;
  int b = wid >> 8;
  int wh = (wid >> 4) & 15, ww = wid & 15;
  int w = tid >> 6, l = tid & 63;
  int li = l & 15, lg = l >> 4;

  // ---- phase 1: stage window tokens (fp16, rows>=49 zeroed) ----
  for (int c = tid; c < 64 * 16; c += 256) {
    int n = c >> 4, k0 = (c & 15) * 8;
    h8 v = {0, 0, 0, 0, 0, 0, 0, 0};
    if (n < NN) {
      int gh = wh * WSZ + n / 7 + shift; if (gh >= HH) gh -= HH;
      int gw = ww * WSZ + n % 7 + shift; if (gw >= HH) gw -= HH;
      v = *(const h8*)(tin + ((size_t)(b * HH + gh) * HH + gw) * CC + k0);
    }
    *(h8*)&sm[OFF_WIN + n * 136 + k0] = v;
  }
  __syncthreads();

  // ---- phase 2: QKV^T = Wqkv(384x128) . win^T -> Q,K [h][64][40], VT [h][32][72] ----
  {
    h8 bW[4][4];
#pragma unroll
    for (int nt = 0; nt < 4; ++nt)
#pragma unroll
      for (int ks = 0; ks < 4; ++ks)
        bW[nt][ks] = *(const h8*)&sm[OFF_WIN + (nt * 16 + li) * 136 + ks * 32 + lg * 8];
    for (int mi = 0; mi < 6; ++mi) {
      int mt = w * 6 + mi;
      const _Float16* arow = qwh + (size_t)(mt * 16 + li) * 128 + lg * 8;
      h8 aA[4];
#pragma unroll
      for (int ks = 0; ks < 4; ++ks) aA[ks] = *(const h8*)(arow + ks * 32);
      f4 acc[4] = {};
#pragma unroll
      for (int ks = 0; ks < 4; ++ks)
#pragma unroll
        for (int nt = 0; nt < 4; ++nt)
          acc[nt] = __builtin_amdgcn_mfma_f32_16x16x32_f16(aA[ks], bW[nt][ks], acc[nt], 0, 0, 0);
      int dbase = mt * 16 + lg * 4;  // output dim (0..383)
      float4 bb = *(const float4*)&qbs[dbase];
#pragma unroll
      for (int nt = 0; nt < 4; ++nt) {
        int i = nt * 16 + li;  // token
        float v0 = acc[nt][0] + bb.x, v1 = acc[nt][1] + bb.y;
        float v2 = acc[nt][2] + bb.z, v3 = acc[nt][3] + bb.w;
        if (mt < 8) {  // Q
          int hq = dbase >> 5, dh = dbase & 31;
          h4 v = {(_Float16)v0, (_Float16)v1, (_Float16)v2, (_Float16)v3};
          *(h4*)&sm[OFF_Q + hq * 2560 + i * 40 + dh] = v;
        } else if (mt < 16) {  // K
          int d = dbase - 128, hq = d >> 5, dh = d & 31;
          h4 v = {(_Float16)v0, (_Float16)v1, (_Float16)v2, (_Float16)v3};
          *(h4*)&sm[OFF_K + hq * 2560 + i * 40 + dh] = v;
        } else {  // V -> VT[d][token]
          int d = dbase - 256, hq = d >> 5, dh = d & 31;
          sm[OFF_VT + hq * 2304 + (dh + 0) * 72 + i] = (_Float16)v0;
          sm[OFF_VT + hq * 2304 + (dh + 1) * 72 + i] = (_Float16)v1;
          sm[OFF_VT + hq * 2304 + (dh + 2) * 72 + i] = (_Float16)v2;
          sm[OFF_VT + hq * 2304 + (dh + 3) * 72 + i] = (_Float16)v3;
        }
      }
    }
  }
  __syncthreads();

  // ---- phase 3: S^T = K . Q^T  (wave = head), bias + mask, softmax ----
  float inv[4];
  {
    int h = w;
    h8 aK[4], bQ[4];
#pragma unroll
    for (int jt = 0; jt < 4; ++jt)
      aK[jt] = *(const h8*)&sm[OFF_K + h * 2560 + (jt * 16 + li) * 40 + lg * 8];
#pragma unroll
    for (int it = 0; it < 4; ++it)
      bQ[it] = *(const h8*)&sm[OFF_Q + h * 2560 + (it * 16 + li) * 40 + lg * 8];
    f4 s[4][4] = {};
#pragma unroll
    for (int jt = 0; jt < 4; ++jt)
#pragma unroll
      for (int it = 0; it < 4; ++it)
        s[jt][it] = __builtin_amdgcn_mfma_f32_16x16x32_f16(aK[jt], bQ[it], s[jt][it], 0, 0, 0);
    // bias (pre-arranged in C-layout) + j>=49 mask
    const float* bT = biasT + h * 4096;
#pragma unroll
    for (int jt = 0; jt < 4; ++jt)
#pragma unroll
      for (int it = 0; it < 4; ++it) {
        f4 bb = *(const f4*)&bT[(jt * 4 + it) * 256 + l * 4];
#pragma unroll
        for (int r = 0; r < 4; ++r) {
          int j = jt * 16 + lg * 4 + r;
          float v = s[jt][it][r] + bb[r];
          s[jt][it][r] = (j < NN) ? v : -1e30f;
        }
      }
    if (shift && (wh == 15 || ww == 15)) {
      int regi[4], regj[4][4];
#pragma unroll
      for (int it = 0; it < 4; ++it) {
        int i = it * 16 + li;
        regi[it] = rid3(wh * WSZ + i / 7) * 3 + rid3(ww * WSZ + i % 7);
      }
#pragma unroll
      for (int jt = 0; jt < 4; ++jt)
#pragma unroll
        for (int r = 0; r < 4; ++r) {
          int j = jt * 16 + lg * 4 + r;
          regj[jt][r] = rid3(wh * WSZ + j / 7) * 3 + rid3(ww * WSZ + j % 7);
        }
#pragma unroll
      for (int jt = 0; jt < 4; ++jt)
#pragma unroll
        for (int it = 0; it < 4; ++it)
#pragma unroll
          for (int r = 0; r < 4; ++r)
            if (regj[jt][r] != regi[it]) s[jt][it][r] -= 100.f;
    }
    __syncthreads();  // all K/Q/win reads done -> P,O overlays safe

    // softmax over j (16 local values + 2 shuffles), write P[h][i][j] fp16
#pragma unroll
    for (int it = 0; it < 4; ++it) {
      float mx = -1e30f;
#pragma unroll
      for (int jt = 0; jt < 4; ++jt)
#pragma unroll
        for (int r = 0; r < 4; ++r) mx = fmaxf(mx, s[jt][it][r]);
      mx = fmaxf(mx, __shfl_xor(mx, 16));
      mx = fmaxf(mx, __shfl_xor(mx, 32));
      float sum = 0.f;
#pragma unroll
      for (int jt = 0; jt < 4; ++jt)
#pragma unroll
        for (int r = 0; r < 4; ++r) {
          float e = __expf(s[jt][it][r] - mx);
          s[jt][it][r] = e;
          sum += e;
        }
      sum += __shfl_xor(sum, 16);
      sum += __shfl_xor(sum, 32);
      inv[it] = 1.f / sum;
    }
#pragma unroll
    for (int it = 0; it < 4; ++it)
#pragma unroll
      for (int jt = 0; jt < 4; ++jt) {
        int i = it * 16 + li, j0 = jt * 16 + lg * 4;
        h4 v = {(_Float16)s[jt][it][0], (_Float16)s[jt][it][1],
                (_Float16)s[jt][it][2], (_Float16)s[jt][it][3]};
        *(h4*)&sm[OFF_P + h * 4608 + i * 72 + j0] = v;
      }
  }

  // ---- phase 4: O^T = V^T . P^T  (wave = head) ----
  {
    int h = w;
    h8 aV[2][2], bP[4][2];
#pragma unroll
    for (int mt = 0; mt < 2; ++mt)
#pragma unroll
      for (int ks = 0; ks < 2; ++ks)
        aV[mt][ks] = *(const h8*)&sm[OFF_VT + h * 2304 + (mt * 16 + li) * 72 + ks * 32 + lg * 8];
#pragma unroll
    for (int nt = 0; nt < 4; ++nt)
#pragma unroll
      for (int ks = 0; ks < 2; ++ks)
        bP[nt][ks] = *(const h8*)&sm[OFF_P + h * 4608 + (nt * 16 + li) * 72 + ks * 32 + lg * 8];
    f4 o[2][4] = {};
#pragma unroll
    for (int ks = 0; ks < 2; ++ks)
#pragma unroll
      for (int mt = 0; mt < 2; ++mt)
#pragma unroll
        for (int nt = 0; nt < 4; ++nt)
          o[mt][nt] = __builtin_amdgcn_mfma_f32_16x16x32_f16(aV[mt][ks], bP[nt][ks], o[mt][nt], 0, 0, 0);
#pragma unroll
    for (int mt = 0; mt < 2; ++mt)
#pragma unroll
      for (int nt = 0; nt < 4; ++nt) {
        int i = nt * 16 + li;
        int d = h * 32 + mt * 16 + lg * 4;
        float is = inv[nt];
        h4 v = {(_Float16)(o[mt][nt][0] * is), (_Float16)(o[mt][nt][1] * is),
                (_Float16)(o[mt][nt][2] * is), (_Float16)(o[mt][nt][3] * is)};
        *(h4*)&sm[OFF_O + i * 136 + d] = v;
      }
  }
  __syncthreads();

  // ---- phase 5: y^T = pw(128x128) . O^T ; fused store ----
  {
    h8 bO[4][4];
#pragma unroll
    for (int nt = 0; nt < 4; ++nt)
#pragma unroll
      for (int ks = 0; ks < 4; ++ks)
        bO[nt][ks] = *(const h8*)&sm[OFF_O + (nt * 16 + li) * 136 + ks * 32 + lg * 8];
    for (int mi = 0; mi < 2; ++mi) {
      int mt = w * 2 + mi;
      const _Float16* arow = pwh + (size_t)(mt * 16 + li) * 128 + lg * 8;
      h8 aP[4];
#pragma unroll
      for (int ks = 0; ks < 4; ++ks) aP[ks] = *(const h8*)(arow + ks * 32);
      f4 acc[4] = {};
#pragma unroll
      for (int ks = 0; ks < 4; ++ks)
#pragma unroll
        for (int nt = 0; nt < 4; ++nt)
          acc[nt] = __builtin_amdgcn_mfma_f32_16x16x32_f16(aP[ks], bO[nt][ks], acc[nt], 0, 0, 0);
      int dbase = mt * 16 + lg * 4;
      float4 bb = *(const float4*)&pb[dbase];
#pragma unroll
      for (int nt = 0; nt < 4; ++nt) {
        int i = nt * 16 + li;
        if (i < NN) {
          int gh = wh * WSZ + i / 7 + shift; if (gh >= HH) gh -= HH;
          int gw = ww * WSZ + i % 7 + shift; if (gw >= HH) gw -= HH;
          float v0 = acc[nt][0] + bb.x, v1 = acc[nt][1] + bb.y;
          float v2 = acc[nt][2] + bb.z, v3 = acc[nt][3] + bb.w;
          if (!writeN) {
            h4 v = {(_Float16)v0, (_Float16)v1, (_Float16)v2, (_Float16)v3};
            *(h4*)&toutB[((size_t)(b * HH + gh) * HH + gw) * CC + dbase] = v;
          } else {
            size_t base = ((size_t)(b * CC + dbase) * HH + gh) * HH + gw;
            outN[base] = v0;
            outN[base + (size_t)HH * HH] = v1;
            outN[base + (size_t)2 * HH * HH] = v2;
            outN[base + (size_t)3 * HH * HH] = v3;
          }
        }
      }
    }
  }
}

extern "C" void kernel_launch(void* const* d_in, const int* in_sizes, int n_in,
                              void* d_out, int out_size, void* d_ws, size_t ws_size,
                              hipStream_t stream) {
  const float* x = (const float*)d_in[0];
  const float* cw = (const float*)d_in[1];
  const float* cb = (const float*)d_in[2];
  const float* qkvw = (const float*)d_in[3];  // (2,384,128)
  const float* qkvb = (const float*)d_in[4];  // (2,384)
  const float* projw = (const float*)d_in[5]; // (2,128,128)
  const float* projb = (const float*)d_in[6]; // (2,128)
  const float* rpb = (const float*)d_in[7];   // (2,169,4)
  float* out = (float*)d_out;

  char* ws = (char*)d_ws;
  _Float16* t0 = (_Float16*)ws;                       // 16*112*112*128 fp16 = 51,380,224 B
  size_t off = (size_t)BB * HH * HH * CC * 2;
  _Float16* qwh = (_Float16*)(ws + off);  off += 2 * 384 * 128 * 2;   // 196,608
  _Float16* pwh = (_Float16*)(ws + off);  off += 2 * 128 * 128 * 2;   // 65,536
  float* qbs = (float*)(ws + off);        off += 2 * 384 * 4;         // 3,072
  float* biasT = (float*)(ws + off);      // 2*16384*4 = 131,072

  prep<<<224, 256, 0, stream>>>(qkvw, qkvb, projw, rpb, qwh, qbs, pwh, biasT);
  conv_embed<<<BB * HH, 256, 0, stream>>>(x, cw, cb, t0);

  // layer 0: no shift, in-place on t0 (windows partition tokens)
  swin_layer<<<4096, 256, 0, stream>>>(t0, t0, nullptr,
      qwh, qbs, pwh, projb, biasT, 0, 0);
  // layer 1: shift=3, fused NCHW transpose into d_out
  swin_layer<<<4096, 256, 0, stream>>>(t0, nullptr, out,
      qwh + 384 * 128, qbs + 384, pwh + 128 * 128, projb + 128,
      biasT + 16384, SH, 1);
}